// Round 11
// baseline (433.017 us; speedup 1.0000x reference)
//
#include <hip/hip_runtime.h>

#define T_ 30
#define H_ 41
#define WD_ 2048
#define NSEC 9
#define FM 50
#define WP 502
#define THRESH 23.0f
#define POOLED_SIZE (NSEC * T_ * FM * WP)   // 6,777,000
#define MARGIN 0.0078125f                   // 2^-7 >= worst-case split error
#define NFRAG 17280                         // 9 sec * 64 fm * 30 tap-octets
#define XC 296                              // LDS cols per shift plane
#define XROWS 9                             // rows j_p + r, 0..8

typedef short short8 __attribute__((ext_vector_type(8)));
typedef short short4v __attribute__((ext_vector_type(4)));
typedef float f32x16 __attribute__((ext_vector_type(16)));

__device__ __forceinline__ unsigned bf16_rne(float f) {
    unsigned u = __float_as_uint(f);
    return (u + 0x7fffu + ((u >> 16) & 1u)) >> 16;
}

// ---------------- prep: W -> 32x32x16 MFMA-ready bf16 hi/lo frags ---------
// gid = (sec*64 + fm)*30 + oct; octet taps t0=8*oct..+7 (240 taps exactly).
// Also initializes the 9 argmin keys.
__global__ __launch_bounds__(256) void prep_kernel(
    const float* __restrict__ Wg, int* __restrict__ wsi,
    uint4* __restrict__ wfh, uint4* __restrict__ wfl)
{
    const int gid = blockIdx.x * 256 + threadIdx.x;
    if (gid < NSEC) wsi[gid] = 0x7fffffff;
    if (gid >= NFRAG) return;
    const int oct = gid % 30;
    const int fm  = (gid / 30) & 63;
    const int sec = gid / 1920;
    const int t0  = oct * 8;
    const bool valid = fm < FM;
    unsigned hh[4], ll[4];
    const float* wp = Wg + ((size_t)sec * FM + (valid ? fm : 0)) * 240 + t0;
    float4 wa = *reinterpret_cast<const float4*>(wp);
    float4 wb = *reinterpret_cast<const float4*>(wp + 4);
    float f[8] = {wa.x, wa.y, wa.z, wa.w, wb.x, wb.y, wb.z, wb.w};
#pragma unroll
    for (int i = 0; i < 4; ++i) {
        float f0 = valid ? f[2 * i] : 0.f;
        float f1 = valid ? f[2 * i + 1] : 0.f;
        unsigned h0 = bf16_rne(f0), h1 = bf16_rne(f1);
        float hf0 = __uint_as_float(h0 << 16), hf1 = __uint_as_float(h1 << 16);
        unsigned l0 = bf16_rne(f0 - hf0), l1 = bf16_rne(f1 - hf1);
        hh[i] = (h1 << 16) | h0;
        ll[i] = (l1 << 16) | l0;
    }
    wfh[gid] = *reinterpret_cast<uint4*>(hh);
    wfl[gid] = *reinterpret_cast<uint4*>(ll);
}

// ---------------- Kernel A: 32x32x16 split-bf16 conv + fire + pool + argmin
// Block 512 thr = 8 waves: wave = (j_p = wid&3, h = wid>>2). Wave computes
// C[m=32 pots stride 8][n=32 fm] for 2 ft-tiles x 4 res (res = 4h+rr).
// A: m = lane&31, k = 8*(lane>>5)+j  (32-wide analog of R6-verified 16x16);
// B: n = lane&31, k = 8*(lane>>5)+j  (prebuilt octet frags);
// C/D: col n = lane&31, row m = (reg&3)+8*(reg>>2)+4*(lane>>5)  (doc-verified).
// off4 = 4h is wave-constant: h=0 waves read pure b128, h=1 pure b64-pairs.
// acc[4] (64 regs) AGPR-parks (R8); B pair transient 8 regs; kc unroll 1.
template <bool PRE>
__global__ __launch_bounds__(512) void conv_pool_kernel(
    const float* __restrict__ x, const float* __restrict__ Wg,
    const uint4* __restrict__ wfh, const uint4* __restrict__ wfl,
    float* __restrict__ out, int* __restrict__ keys)
{
    __shared__ __align__(16) unsigned short xh[4][XROWS][XC];  // 20.8 KB
    __shared__ __align__(16) unsigned short xl[4][XROWS][XC];  // 20.8 KB
    __shared__ unsigned lmask[8][64];
    __shared__ int red[512];

    const int b       = blockIdx.x;
    const int coltile = b & 7;             // 8 coltiles * 256 pot cols
    const int tt      = (b >> 3) % T_;
    const int sec     = b / 240;
    const int w0      = coltile * 256;     // pot-col base
    const int rowbase = 4 * sec;           // <= 32; rows used <= 40 < 41
    const int tid     = threadIdx.x;

    // ---- stage x: 9 rows x 296 cols -> hi/lo u16, 4 shifted copies ----
    for (int i = tid; i < XROWS * 74; i += 512) {
        const int row = i / 74;
        const int c4  = i % 74;
        const int gc  = w0 + 4 * c4;
        float4 v;
        if (gc + 3 < WD_) {
            v = *reinterpret_cast<const float4*>(
                x + ((size_t)tt * H_ + rowbase + row) * WD_ + gc);
        } else {
            v.x = v.y = v.z = v.w = 0.f;
        }
        float f[4] = {v.x, v.y, v.z, v.w};
        unsigned short hq[4], lq[4];
#pragma unroll
        for (int e = 0; e < 4; ++e) {
            unsigned hbits = bf16_rne(f[e]);
            float hf = __uint_as_float(hbits << 16);
            unsigned lbits = bf16_rne(f[e] - hf);
            hq[e] = (unsigned short)hbits;
            lq[e] = (unsigned short)lbits;
        }
#pragma unroll
        for (int S = 0; S < 4; ++S)
#pragma unroll
            for (int e = 0; e < 4; ++e) {
                const int j = 4 * c4 + e - S;
                if (j >= 0 && j < XC) { xh[S][row][j] = hq[e]; xl[S][row][j] = lq[e]; }
            }
    }
    __syncthreads();

    const int L   = tid & 63;
    const int wid = tid >> 6;
    const int j_p = wid & 3;        // pot row
    const int h   = wid >> 2;       // res half: res = 4h + rr
    const int n32 = L & 31;         // A: m; B/C/D: n (fm)
    const int hA  = L >> 5;         // k-offset 8*hA; C/D row += 4*hA

    // aoff at kc=0: (j_p + r=0)*XC + c0(=8hA) + 8*m + off4(=4h)
    const int aoff0 = j_p * XC + 8 * hA + 8 * n32 + 4 * h;

    unsigned mask = 0;

#pragma unroll 1
    for (int ft = 0; ft < 2; ++ft) {
        const int fm = ft * 32 + n32;
        f32x16 acc[4];
#pragma unroll
        for (int rr = 0; rr < 4; ++rr)
#pragma unroll
            for (int e = 0; e < 16; ++e) acc[rr][e] = 0.f;

        const int fbase = (sec * 64 + ft * 32 + n32) * 30 + hA;
        int aoff = aoff0;
        int c0   = 8 * hA;

#pragma unroll 1
        for (int kc = 0; kc < 15; ++kc) {
            short8 bh, bl;
            if (PRE) {
                union { uint4 u; short8 s; } c1, c2;
                c1.u = wfh[fbase + 2 * kc]; bh = c1.s;
                c2.u = wfl[fbase + 2 * kc]; bl = c2.s;
            } else {
                const int t0 = 16 * kc + 8 * hA;     // < 240 always
                const bool wv = fm < FM;
                const float* wp = Wg + ((size_t)sec * FM + (wv ? fm : 0)) * 240 + t0;
                float4 wa = *reinterpret_cast<const float4*>(wp);
                float4 wb = *reinterpret_cast<const float4*>(wp + 4);
                float f[8] = {wa.x, wa.y, wa.z, wa.w, wb.x, wb.y, wb.z, wb.w};
                unsigned hh[4], ll[4];
#pragma unroll
                for (int i = 0; i < 4; ++i) {
                    float f0 = wv ? f[2 * i] : 0.f;
                    float f1 = wv ? f[2 * i + 1] : 0.f;
                    unsigned h0 = bf16_rne(f0), h1 = bf16_rne(f1);
                    float hf0 = __uint_as_float(h0 << 16), hf1 = __uint_as_float(h1 << 16);
                    unsigned l0 = bf16_rne(f0 - hf0), l1 = bf16_rne(f1 - hf1);
                    hh[i] = (h1 << 16) | h0;
                    ll[i] = (l1 << 16) | l0;
                }
                bh = *reinterpret_cast<short8*>(hh);
                bl = *reinterpret_cast<short8*>(ll);
            }

#pragma unroll
            for (int rr = 0; rr < 4; ++rr) {
                const unsigned short* hb = &xh[rr][0][0] + aoff;
                const unsigned short* lb = &xl[rr][0][0] + aoff;
                short8 ah, al;
                if (h == 0) {                         // 16B-aligned: b128
                    ah = *reinterpret_cast<const short8*>(hb);
                    al = *reinterpret_cast<const short8*>(lb);
                } else {                              // 8B-aligned: 2x b64
                    short4v h0 = *reinterpret_cast<const short4v*>(hb);
                    short4v h1 = *reinterpret_cast<const short4v*>(hb + 4);
                    short4v l0 = *reinterpret_cast<const short4v*>(lb);
                    short4v l1 = *reinterpret_cast<const short4v*>(lb + 4);
                    ah = __builtin_shufflevector(h0, h1, 0, 1, 2, 3, 4, 5, 6, 7);
                    al = __builtin_shufflevector(l0, l1, 0, 1, 2, 3, 4, 5, 6, 7);
                }
                acc[rr] = __builtin_amdgcn_mfma_f32_32x32x16_bf16(ah, bh, acc[rr], 0, 0, 0);
                acc[rr] = __builtin_amdgcn_mfma_f32_32x32x16_bf16(al, bh, acc[rr], 0, 0, 0);
                acc[rr] = __builtin_amdgcn_mfma_f32_32x32x16_bf16(ah, bl, acc[rr], 0, 0, 0);
            }
            // advance tap run: c0 += 16 within 40-col kernel row
            aoff += 16; c0 += 16;
            if (c0 >= 40) { c0 -= 40; aoff += XC - 40; }
        }

        // ---- epilogue: repair borderline, set pool bits ----
#pragma unroll
        for (int rr = 0; rr < 4; ++rr) {
            const int res = 4 * h + rr;
#pragma unroll
            for (int reg = 0; reg < 16; ++reg) {
                float v = acc[rr][reg];
                const int m   = (reg & 3) + 8 * (reg >> 2) + 4 * hA;
                const int pcg = w0 + res + 8 * m;     // global pot col
                const bool valid = (fm < FM) && (pcg <= 2007);
                if (valid && __builtin_fabsf(v - THRESH) < MARGIN) {
                    float pot = 0.f;
#pragma unroll 1
                    for (int r2 = 0; r2 < 6; ++r2) {
                        const float* xr = x + ((size_t)tt * H_ + rowbase + j_p + r2) * WD_ + pcg;
                        const float* wr = Wg + (size_t)sec * FM * 240 + (size_t)fm * 240 + r2 * 40;
#pragma unroll 1
                        for (int c = 0; c < 40; ++c)
                            pot = fmaf(xr[c], wr[c], pot);
                    }
                    v = pot;
                }
                if (v > THRESH)
                    mask |= 1u << (ft * 16 + reg);    // pooled col p = 2m + h
            }
        }
    }

    lmask[wid][L] = mask;
    __syncthreads();

    // ---- cross-wave OR + pooled write + fused first-spike argmin ----
    // block covers 64 fm x 64 pooled cols
    int mykey = 0x7fffffff;
    for (int e = tid; e < 4096; e += 512) {
        const int fmo = e >> 6, p = e & 63;
        const int m   = p >> 1, h2 = p & 1;
        const int hA2 = (m >> 2) & 1;
        const int reg = (m & 3) + 4 * (m >> 3);
        const int lane = 32 * hA2 + (fmo & 31);
        const int bit  = (fmo >> 5) * 16 + reg;
        const unsigned bits = lmask[4 * h2 + 0][lane] | lmask[4 * h2 + 1][lane] |
                              lmask[4 * h2 + 2][lane] | lmask[4 * h2 + 3][lane];
        const int pg  = coltile * 64 + p;
        const int spk = (bits >> bit) & 1u;
        if (fmo < FM && pg < WP) {
            out[((size_t)(sec * T_ + tt) * FM + fmo) * WP + pg] = spk ? 1.0f : 0.0f;
            if (spk) mykey = min(mykey, fmo * WP + pg);
        }
    }
    red[tid] = mykey;
    __syncthreads();
    for (int s = 256; s > 0; s >>= 1) {
        if (tid < s) red[tid] = min(red[tid], red[tid + s]);
        __syncthreads();
    }
    if (tid == 0 && red[0] != 0x7fffffff)
        atomicMin(&keys[sec], (tt << 15) | red[0]);
}

// ---------------- init (fallback only) ----------------
__global__ void init_kernel(int* __restrict__ ws)
{
    if (threadIdx.x < NSEC) ws[threadIdx.x] = 0x7fffffff;
}

// ---------------- Kernel D: finalize winners ----------------
__global__ void finalize_kernel(const int* __restrict__ ws, float* __restrict__ out)
{
    const int i = threadIdx.x;
    if (i < NSEC) {
        const int key = ws[i];
        float feat;
        if (key == 0x7fffffff) feat = -1.0f;
        else                   feat = (float)((key & 32767) / WP);
        out[POOLED_SIZE + i] = feat;
    }
}

extern "C" void kernel_launch(void* const* d_in, const int* in_sizes, int n_in,
                              void* d_out, int out_size, void* d_ws, size_t ws_size,
                              hipStream_t stream) {
    const float* x  = (const float*)d_in[0];
    const float* Wg = (const float*)d_in[1];
    float* out = (float*)d_out;
    int*   wsi = (int*)d_ws;
    uint4* wfh = (uint4*)((char*)d_ws + 256);
    uint4* wfl = wfh + NFRAG;

    const bool pre = ws_size >= 256 + (size_t)NFRAG * 16 * 2;   // 553 KB
    if (pre) {
        prep_kernel<<<dim3(68), dim3(256), 0, stream>>>(Wg, wsi, wfh, wfl);
        conv_pool_kernel<true><<<dim3(2160), dim3(512), 0, stream>>>(x, Wg, wfh, wfl, out, wsi);
    } else {
        init_kernel<<<dim3(1), dim3(64), 0, stream>>>(wsi);
        conv_pool_kernel<false><<<dim3(2160), dim3(512), 0, stream>>>(x, Wg, wfh, wfl, out, wsi);
    }
    finalize_kernel<<<dim3(1), dim3(16), 0, stream>>>(wsi, out);
}

// Round 12
// 361.514 us; speedup vs baseline: 1.1978x; 1.1978x over previous
//
#include <hip/hip_runtime.h>

#define T_ 30
#define H_ 41
#define WD_ 2048
#define NSEC 9
#define FM 50
#define WP 502
#define THRESH 23.0f
#define POOLED_SIZE (NSEC * T_ * FM * WP)   // 6,777,000
#define MARGIN 0.0078125f                   // 2^-7 >= worst-case split error
#define NFRAG 17280                         // 9 sec * 64 fm * 30 tap-octets
#define XC 296                              // LDS cols per shift plane
#define XROWS 9

typedef short short8 __attribute__((ext_vector_type(8)));
typedef short short4v __attribute__((ext_vector_type(4)));
typedef float f32x16 __attribute__((ext_vector_type(16)));

__device__ __forceinline__ unsigned bf16_rne(float f) {
    unsigned u = __float_as_uint(f);
    return (u + 0x7fffu + ((u >> 16) & 1u)) >> 16;
}

// ---------------- prep: W -> 32x32x16 MFMA-ready bf16 hi/lo frags ---------
// gid = (sec*64 + fm)*30 + oct; octet taps t0=8*oct..+7. Also inits keys.
__global__ __launch_bounds__(256) void prep_kernel(
    const float* __restrict__ Wg, int* __restrict__ wsi,
    uint4* __restrict__ wfh, uint4* __restrict__ wfl)
{
    const int gid = blockIdx.x * 256 + threadIdx.x;
    if (gid < NSEC) wsi[gid] = 0x7fffffff;
    if (gid >= NFRAG) return;
    const int oct = gid % 30;
    const int fm  = (gid / 30) & 63;
    const int sec = gid / 1920;
    const int t0  = oct * 8;
    const bool valid = fm < FM;
    unsigned hh[4], ll[4];
    const float* wp = Wg + ((size_t)sec * FM + (valid ? fm : 0)) * 240 + t0;
    float4 wa = *reinterpret_cast<const float4*>(wp);
    float4 wb = *reinterpret_cast<const float4*>(wp + 4);
    float f[8] = {wa.x, wa.y, wa.z, wa.w, wb.x, wb.y, wb.z, wb.w};
#pragma unroll
    for (int i = 0; i < 4; ++i) {
        float f0 = valid ? f[2 * i] : 0.f;
        float f1 = valid ? f[2 * i + 1] : 0.f;
        unsigned h0 = bf16_rne(f0), h1 = bf16_rne(f1);
        float hf0 = __uint_as_float(h0 << 16), hf1 = __uint_as_float(h1 << 16);
        unsigned l0 = bf16_rne(f0 - hf0), l1 = bf16_rne(f1 - hf1);
        hh[i] = (h1 << 16) | h0;
        ll[i] = (l1 << 16) | l0;
    }
    wfh[gid] = *reinterpret_cast<uint4*>(hh);
    wfl[gid] = *reinterpret_cast<uint4*>(ll);
}

// ---------------- Kernel A: 32x32x16 split-bf16 conv + fire + pool + argmin
// R11's verified layouts; R12 retile for occupancy: 8 waves = (j_p 0..3) x
// (ft 0..1). Wave processes res PAIRS (rr, rr+4): shared plane S=rr, shared
// B frags, acc = 2x16 = 32 AGPRs only (R11's 64+dual-ft -> 116 VGPR, 18% occ
// was the regression). Per kc: 1 B pair (L2) + 6 LDS reads + 6 MFMA.
// Loops rr/kc stay `#pragma unroll 1` (R7 spill lesson).
template <bool PRE>
__global__ __launch_bounds__(512) void conv_pool_kernel(
    const float* __restrict__ x, const float* __restrict__ Wg,
    const uint4* __restrict__ wfh, const uint4* __restrict__ wfl,
    float* __restrict__ out, int* __restrict__ keys)
{
    __shared__ __align__(16) unsigned short xh[4][XROWS][XC];  // 20.8 KB
    __shared__ __align__(16) unsigned short xl[4][XROWS][XC];  // 20.8 KB
    __shared__ unsigned lmask[8][64];
    __shared__ int red[512];

    const int b       = blockIdx.x;
    const int coltile = b & 7;             // 8 coltiles * 256 pot cols
    const int tt      = (b >> 3) % T_;
    const int sec     = b / 240;
    const int w0      = coltile * 256;
    const int rowbase = 4 * sec;           // rows used <= 40 < 41
    const int tid     = threadIdx.x;

    // ---- stage x: 9 rows x 296 cols -> hi/lo u16, 4 shifted copies ----
    for (int i = tid; i < XROWS * 74; i += 512) {
        const int row = i / 74;
        const int c4  = i % 74;
        const int gc  = w0 + 4 * c4;
        float4 v;
        if (gc + 3 < WD_) {
            v = *reinterpret_cast<const float4*>(
                x + ((size_t)tt * H_ + rowbase + row) * WD_ + gc);
        } else {
            v.x = v.y = v.z = v.w = 0.f;
        }
        float f[4] = {v.x, v.y, v.z, v.w};
        unsigned short hq[4], lq[4];
#pragma unroll
        for (int e = 0; e < 4; ++e) {
            unsigned hbits = bf16_rne(f[e]);
            float hf = __uint_as_float(hbits << 16);
            unsigned lbits = bf16_rne(f[e] - hf);
            hq[e] = (unsigned short)hbits;
            lq[e] = (unsigned short)lbits;
        }
#pragma unroll
        for (int S = 0; S < 4; ++S)
#pragma unroll
            for (int e = 0; e < 4; ++e) {
                const int j = 4 * c4 + e - S;
                if (j >= 0 && j < XC) { xh[S][row][j] = hq[e]; xl[S][row][j] = lq[e]; }
            }
    }
    __syncthreads();

    const int L   = tid & 63;
    const int wid = tid >> 6;
    const int j_p = wid & 3;        // pot row
    const int ft  = wid >> 2;       // fm tile (32 fm each)
    const int n32 = L & 31;         // A: m; B/C/D: n
    const int hA  = L >> 5;         // k-offset 8*hA; C/D row += 4*hA

    const int fbase = (sec * 64 + ft * 32 + n32) * 30 + hA;
    const int aoff_base = j_p * XC + 8 * hA + 8 * n32;

    unsigned mask = 0;

#pragma unroll 1
    for (int rr = 0; rr < 4; ++rr) {          // res pair (rr, rr+4)
        const unsigned short* hb = &xh[rr][0][0];
        const unsigned short* lb = &xl[rr][0][0];
        f32x16 acc0, acc1;
#pragma unroll
        for (int e = 0; e < 16; ++e) { acc0[e] = 0.f; acc1[e] = 0.f; }

        int aoff = aoff_base;
        int c0   = 8 * hA;
#pragma unroll 1
        for (int kc = 0; kc < 15; ++kc) {
            short8 bh, bl;
            if (PRE) {
                union { uint4 u; short8 s; } c1, c2;
                c1.u = wfh[fbase + 2 * kc]; bh = c1.s;
                c2.u = wfl[fbase + 2 * kc]; bl = c2.s;
            } else {
                const int t0 = 16 * kc + 8 * hA;
                const int fm = ft * 32 + n32;
                const bool wv = fm < FM;
                const float* wp = Wg + ((size_t)sec * FM + (wv ? fm : 0)) * 240 + t0;
                float4 wa = *reinterpret_cast<const float4*>(wp);
                float4 wb = *reinterpret_cast<const float4*>(wp + 4);
                float f[8] = {wa.x, wa.y, wa.z, wa.w, wb.x, wb.y, wb.z, wb.w};
                unsigned hh[4], ll[4];
#pragma unroll
                for (int i = 0; i < 4; ++i) {
                    float f0 = wv ? f[2 * i] : 0.f;
                    float f1 = wv ? f[2 * i + 1] : 0.f;
                    unsigned h0 = bf16_rne(f0), h1 = bf16_rne(f1);
                    float hf0 = __uint_as_float(h0 << 16), hf1 = __uint_as_float(h1 << 16);
                    unsigned l0 = bf16_rne(f0 - hf0), l1 = bf16_rne(f1 - hf1);
                    hh[i] = (h1 << 16) | h0;
                    ll[i] = (l1 << 16) | l0;
                }
                bh = *reinterpret_cast<short8*>(hh);
                bl = *reinterpret_cast<short8*>(ll);
            }

            // res = rr: 16B-aligned b128; res = rr+4: +4 cols, 2x b64
            short8 ah0 = *reinterpret_cast<const short8*>(hb + aoff);
            short8 al0 = *reinterpret_cast<const short8*>(lb + aoff);
            short4v h0 = *reinterpret_cast<const short4v*>(hb + aoff + 4);
            short4v h1 = *reinterpret_cast<const short4v*>(hb + aoff + 8);
            short4v l0 = *reinterpret_cast<const short4v*>(lb + aoff + 4);
            short4v l1 = *reinterpret_cast<const short4v*>(lb + aoff + 8);
            short8 ah1 = __builtin_shufflevector(h0, h1, 0, 1, 2, 3, 4, 5, 6, 7);
            short8 al1 = __builtin_shufflevector(l0, l1, 0, 1, 2, 3, 4, 5, 6, 7);

            acc0 = __builtin_amdgcn_mfma_f32_32x32x16_bf16(ah0, bh, acc0, 0, 0, 0);
            acc1 = __builtin_amdgcn_mfma_f32_32x32x16_bf16(ah1, bh, acc1, 0, 0, 0);
            acc0 = __builtin_amdgcn_mfma_f32_32x32x16_bf16(al0, bh, acc0, 0, 0, 0);
            acc1 = __builtin_amdgcn_mfma_f32_32x32x16_bf16(al1, bh, acc1, 0, 0, 0);
            acc0 = __builtin_amdgcn_mfma_f32_32x32x16_bf16(ah0, bl, acc0, 0, 0, 0);
            acc1 = __builtin_amdgcn_mfma_f32_32x32x16_bf16(ah1, bl, acc1, 0, 0, 0);

            aoff += 16; c0 += 16;
            if (c0 >= 40) { c0 -= 40; aoff += XC - 40; }
        }

        // ---- epilogue: repair borderline, set pool bits (both res) ----
#pragma unroll
        for (int half = 0; half < 2; ++half) {
            const f32x16 acc = half ? acc1 : acc0;
            const int res = rr + 4 * half;
            const int fm  = ft * 32 + n32;
#pragma unroll
            for (int reg = 0; reg < 16; ++reg) {
                float v = acc[reg];
                const int m   = (reg & 3) + 8 * (reg >> 2) + 4 * hA;
                const int pcg = w0 + res + 8 * m;
                const bool valid = (fm < FM) && (pcg <= 2007);
                if (valid && __builtin_fabsf(v - THRESH) < MARGIN) {
                    float pot = 0.f;
#pragma unroll 1
                    for (int r2 = 0; r2 < 6; ++r2) {
                        const float* xr = x + ((size_t)tt * H_ + rowbase + j_p + r2) * WD_ + pcg;
                        const float* wr = Wg + (size_t)sec * FM * 240 + (size_t)fm * 240 + r2 * 40;
#pragma unroll 1
                        for (int c = 0; c < 40; ++c)
                            pot = fmaf(xr[c], wr[c], pot);
                    }
                    v = pot;
                }
                if (v > THRESH)
                    mask |= 1u << (reg + 16 * half);  // bit = reg + 16*(res>>2)
            }
        }
    }

    lmask[wid][L] = mask;
    __syncthreads();

    // ---- cross-wave OR (over j_p) + pooled write + fused argmin ----
    int mykey = 0x7fffffff;
    for (int e = tid; e < 4096; e += 512) {
        const int fmo = e >> 6, p = e & 63;       // p = 2m + (res>>2)
        const int rh  = p & 1, m = p >> 1;
        const int hA2 = (m >> 2) & 1;
        const int reg = (m & 3) + 4 * (m >> 3);
        const int lane = 32 * hA2 + (fmo & 31);
        const int ftg  = fmo >> 5;
        const int bit  = reg + 16 * rh;
        const unsigned bits = lmask[4 * ftg + 0][lane] | lmask[4 * ftg + 1][lane] |
                              lmask[4 * ftg + 2][lane] | lmask[4 * ftg + 3][lane];
        const int pg  = coltile * 64 + p;
        const int spk = (bits >> bit) & 1u;
        if (fmo < FM && pg < WP) {
            out[((size_t)(sec * T_ + tt) * FM + fmo) * WP + pg] = spk ? 1.0f : 0.0f;
            if (spk) mykey = min(mykey, fmo * WP + pg);
        }
    }
    red[tid] = mykey;
    __syncthreads();
    for (int s = 256; s > 0; s >>= 1) {
        if (tid < s) red[tid] = min(red[tid], red[tid + s]);
        __syncthreads();
    }
    if (tid == 0 && red[0] != 0x7fffffff)
        atomicMin(&keys[sec], (tt << 15) | red[0]);
}

// ---------------- init (fallback only) ----------------
__global__ void init_kernel(int* __restrict__ ws)
{
    if (threadIdx.x < NSEC) ws[threadIdx.x] = 0x7fffffff;
}

// ---------------- Kernel D: finalize winners ----------------
__global__ void finalize_kernel(const int* __restrict__ ws, float* __restrict__ out)
{
    const int i = threadIdx.x;
    if (i < NSEC) {
        const int key = ws[i];
        float feat;
        if (key == 0x7fffffff) feat = -1.0f;
        else                   feat = (float)((key & 32767) / WP);
        out[POOLED_SIZE + i] = feat;
    }
}

extern "C" void kernel_launch(void* const* d_in, const int* in_sizes, int n_in,
                              void* d_out, int out_size, void* d_ws, size_t ws_size,
                              hipStream_t stream) {
    const float* x  = (const float*)d_in[0];
    const float* Wg = (const float*)d_in[1];
    float* out = (float*)d_out;
    int*   wsi = (int*)d_ws;
    uint4* wfh = (uint4*)((char*)d_ws + 256);
    uint4* wfl = wfh + NFRAG;

    const bool pre = ws_size >= 256 + (size_t)NFRAG * 16 * 2;   // 553 KB
    if (pre) {
        prep_kernel<<<dim3(68), dim3(256), 0, stream>>>(Wg, wsi, wfh, wfl);
        conv_pool_kernel<true><<<dim3(2160), dim3(512), 0, stream>>>(x, Wg, wfh, wfl, out, wsi);
    } else {
        init_kernel<<<dim3(1), dim3(64), 0, stream>>>(wsi);
        conv_pool_kernel<false><<<dim3(2160), dim3(512), 0, stream>>>(x, Wg, wfh, wfl, out, wsi);
    }
    finalize_kernel<<<dim3(1), dim3(16), 0, stream>>>(wsi, out);
}